// Round 1
// baseline (24.302 us; speedup 1.0000x reference)
//
#include <hip/hip_runtime.h>

#define B_ 16
#define Q_ 2048
#define K_ 1024
#define G_ 512
#define M_ 4096

__device__ __forceinline__ float wave_sum64(float v) {
#pragma unroll
  for (int o = 32; o > 0; o >>= 1) v += __shfl_down(v, o, 64);
  return v;
}

__device__ __forceinline__ bool pt_in_box(float pxv, float pyv,
                                          float bx, float by, float bl, float bw,
                                          float bc, float bs) {
  float dx = pxv - bx, dy = pyv - by;
  float qx = dx * bc + dy * bs;
  float qy = -dx * bs + dy * bc;
  return (fabsf(qx) <= bl * 0.5f + 1e-5f) && (fabsf(qy) <= bw * 0.5f + 1e-5f);
}

__global__ __launch_bounds__(64) void pair_loss_kernel(
    const float* __restrict__ pred_boxes, const float* __restrict__ pred_ious,
    const float* __restrict__ gt_boxes, const int* __restrict__ topk_indexes,
    const int* __restrict__ batch_idx, const int* __restrict__ src_idx,
    const int* __restrict__ tgt_idx, float* __restrict__ partials) {
  const int i = blockIdx.x * 64 + threadIdx.x;
  float lb = 0.f, lg = 0.f, lr = 0.f, li = 0.f;
  if (i < M_) {
    const int b = batch_idx[i];
    const int s = src_idx[i];
    const int t = tgt_idx[i];
    const int tk = topk_indexes[b * K_ + s];
    const float* mp = pred_boxes + ((size_t)b * Q_ + tk) * 7;
    const float* mt = gt_boxes + ((size_t)b * G_ + t) * 7;
    const float pim = pred_ious[b * Q_ + tk];
    float A[7], Bv[7];
#pragma unroll
    for (int j = 0; j < 7; ++j) { A[j] = mp[j]; Bv[j] = mt[j]; }

    // ---- loss_bbox / loss_rad (raw boxes) ----
#pragma unroll
    for (int j = 0; j < 6; ++j) lb += fabsf(A[j] - Bv[j]);
    lr = fabsf(A[6] - Bv[6]);

    // ---- axis-aligned 3D GIoU on raw boxes (diagonal only) ----
    {
      float vol1 = 1.f, vol2 = 1.f, inter = 1.f, volc = 1.f;
#pragma unroll
      for (int j = 0; j < 3; ++j) {
        float l1 = A[j] - 0.5f * A[3 + j], r1 = A[j] + 0.5f * A[3 + j];
        float l2 = Bv[j] - 0.5f * Bv[3 + j], r2 = Bv[j] + 0.5f * Bv[3 + j];
        vol1 *= (r1 - l1);
        vol2 *= (r2 - l2);
        inter *= fmaxf(fminf(r1, r2) - fmaxf(l1, l2), 0.f);
        volc *= fmaxf(fmaxf(r1, r2) - fminf(l1, l2), 0.f);
      }
      float uni = vol1 + vol2 - inter;
      float iou = inter / fmaxf(uni, 1e-7f);
      float giou = iou - (volc - uni) / fmaxf(volc, 1e-7f);
      lg = 1.f - giou;
    }

    // ---- decode boxes ----
    float ax = A[0] * 150.4f + -75.2f;
    float ay = A[1] * 150.4f + -75.2f;
    float az = A[2] * 6.0f + -2.0f;
    float al = A[3] * 20.0f + 0.05f;
    float aw = A[4] * 20.0f + 0.05f;
    float ah = A[5] * 8.0f + 0.05f;
    float arad = A[6] * 6.2831853071795862f - 3.1415926535897931f;
    float bx = Bv[0] * 150.4f + -75.2f;
    float by = Bv[1] * 150.4f + -75.2f;
    float bz = Bv[2] * 6.0f + -2.0f;
    float bl = Bv[3] * 20.0f + 0.05f;
    float bw = Bv[4] * 20.0f + 0.05f;
    float bh = Bv[5] * 8.0f + 0.05f;
    float brad = Bv[6] * 6.2831853071795862f - 3.1415926535897931f;

    // ---- BEV corners ----
    float cA = cosf(arad), sA = sinf(arad);
    float cB = cosf(brad), sB = sinf(brad);
    float ahx = al * 0.5f, ahy = aw * 0.5f;
    float bhx = bl * 0.5f, bhy = bw * 0.5f;
    const float sgx[4] = {1.f, 1.f, -1.f, -1.f};
    const float sgy[4] = {1.f, -1.f, -1.f, 1.f};
    float cax[4], cay[4], cbx[4], cby[4];
#pragma unroll
    for (int k = 0; k < 4; ++k) {
      float lx = sgx[k] * ahx, ly = sgy[k] * ahy;
      cax[k] = ax + lx * cA - ly * sA;
      cay[k] = ay + lx * sA + ly * cA;
      lx = sgx[k] * bhx; ly = sgy[k] * bhy;
      cbx[k] = bx + lx * cB - ly * sB;
      cby[k] = by + lx * sB + ly * cB;
    }

    // ---- 24 candidate points + mask bits ----
    float px[24], py[24];
    unsigned mbits = 0u;
#pragma unroll
    for (int k = 0; k < 4; ++k) {
      px[k] = cax[k]; py[k] = cay[k];
      px[4 + k] = cbx[k]; py[4 + k] = cby[k];
      if (pt_in_box(cax[k], cay[k], bx, by, bl, bw, cB, sB)) mbits |= 1u << k;
      if (pt_in_box(cbx[k], cby[k], ax, ay, al, aw, cA, sA)) mbits |= 1u << (4 + k);
    }
#pragma unroll
    for (int j = 0; j < 4; ++j) {
      float a0x = cax[j], a0y = cay[j];
      float dax = cax[(j + 1) & 3] - a0x, day = cay[(j + 1) & 3] - a0y;
#pragma unroll
      for (int k = 0; k < 4; ++k) {
        float e0x = cbx[k], e0y = cby[k];
        float dbx = cbx[(k + 1) & 3] - e0x, dby = cby[(k + 1) & 3] - e0y;
        float dpx = e0x - a0x, dpy = e0y - a0y;
        float den = dax * dby - day * dbx;
        bool dok = fabsf(den) > 1e-8f;
        float dens = dok ? den : 1.f;
        float tt = (dpx * dby - dpy * dbx) / dens;
        float uu = (dpx * day - dpy * dax) / dens;
        bool ok = dok && (tt >= 0.f) && (tt <= 1.f) && (uu >= 0.f) && (uu <= 1.f);
        int p = 8 + j * 4 + k;
        px[p] = a0x + tt * dax;
        py[p] = a0y + tt * day;
        if (ok) mbits |= 1u << p;
      }
    }

    // ---- centroid of masked points ----
    float cntf = 0.f, sx = 0.f, sy = 0.f;
#pragma unroll
    for (int p = 0; p < 24; ++p) {
      float w = ((mbits >> p) & 1u) ? 1.f : 0.f;
      cntf += w;
      sx += px[p] * w;
      sy += py[p] * w;
    }
    float cd = fmaxf(cntf, 1.f);
    float cenx = sx / cd, ceny = sy / cd;

    // ---- angles (unmasked -> 1e9, matches reference's where(mask, ang, 1e9)) ----
    float ang[24];
#pragma unroll
    for (int p = 0; p < 24; ++p) {
      ang[p] = ((mbits >> p) & 1u) ? atan2f(py[p] - ceny, px[p] - cenx) : 1e9f;
    }

    // ---- stable angular rank + scatter into sorted order ----
    // Reference: stable argsort of 24 angles; masked points (ang < 1e9) sort
    // first; unmasked get replaced by p0 = first sorted point, whose shoelace
    // terms all vanish. So area == shoelace over the cnt sorted masked points.
    float sxx[24], syy[24];
    int cnti = 0;
    for (int p = 0; p < 24; ++p) {
      if ((mbits >> p) & 1u) {
        float ap = ang[p];
        int r = 0;
        for (int q = 0; q < 24; ++q) {
          if ((mbits >> q) & 1u) {
            float aq = ang[q];
            r += (aq < ap || (aq == ap && q < p)) ? 1 : 0;
          }
        }
        sxx[r] = px[p];
        syy[r] = py[p];
        ++cnti;
      }
    }
    float area2 = 0.f;
    for (int p = 0; p < cnti; ++p) {
      int q = (p + 1 == cnti) ? 0 : p + 1;
      area2 += sxx[p] * syy[q] - sxx[q] * syy[p];
    }
    float area = 0.5f * fabsf(area2);
    float inter_bev = (cnti >= 3) ? area : 0.f;

    // ---- z overlap + 3D IoU ----
    float zlo = fmaxf(az - ah * 0.5f, bz - bh * 0.5f);
    float zhi = fminf(az + ah * 0.5f, bz + bh * 0.5f);
    float inter3 = inter_bev * fmaxf(zhi - zlo, 0.f);
    float v1 = al * aw * ah, v2 = bl * bw * bh;
    float iou3 = inter3 / fmaxf(v1 + v2 - inter3, 1e-7f);
    float iou_t = iou3 * 2.f - 1.f;
    li = fabsf(pim - iou_t);
  }

  lb = wave_sum64(lb);
  lg = wave_sum64(lg);
  lr = wave_sum64(lr);
  li = wave_sum64(li);
  if (threadIdx.x == 0) {
    ((float4*)partials)[blockIdx.x] = make_float4(lb, lg, lr, li);
  }
}

__global__ __launch_bounds__(64) void finalize_kernel(
    const float* __restrict__ partials, const int* __restrict__ nb_ptr,
    float* __restrict__ out) {
  const int lane = threadIdx.x;
  const float4 p = ((const float4*)partials)[lane];
  float a = wave_sum64(p.x);
  float b = wave_sum64(p.y);
  float c = wave_sum64(p.z);
  float d = wave_sum64(p.w);
  if (lane == 0) {
    float nb = (float)nb_ptr[0];
    out[0] = a / nb;
    out[1] = b / nb;
    out[2] = c / nb;
    out[3] = d / nb;
  }
}

extern "C" void kernel_launch(void* const* d_in, const int* in_sizes, int n_in,
                              void* d_out, int out_size, void* d_ws, size_t ws_size,
                              hipStream_t stream) {
  const float* pred_boxes = (const float*)d_in[0];
  const float* pred_ious  = (const float*)d_in[1];
  const float* gt_boxes   = (const float*)d_in[2];
  const int* topk         = (const int*)d_in[3];
  const int* bidx         = (const int*)d_in[4];
  const int* sidx         = (const int*)d_in[5];
  const int* tidx         = (const int*)d_in[6];
  const int* nb           = (const int*)d_in[7];
  float* partials = (float*)d_ws;  // 64 blocks * 4 floats = 1 KiB

  pair_loss_kernel<<<dim3(M_ / 64), dim3(64), 0, stream>>>(
      pred_boxes, pred_ious, gt_boxes, topk, bidx, sidx, tidx, partials);
  finalize_kernel<<<dim3(1), dim3(64), 0, stream>>>(partials, nb, (float*)d_out);
}

// Round 2
// 12.764 us; speedup vs baseline: 1.9040x; 1.9040x over previous
//
#include <hip/hip_runtime.h>

#define B_ 16
#define Q_ 2048
#define K_ 1024
#define G_ 512
#define M_ 4096

__device__ __forceinline__ float bsum64(float v) {
#pragma unroll
  for (int o = 1; o < 64; o <<= 1) v += __shfl_xor(v, o, 64);
  return v;
}

__device__ __forceinline__ void corner_xy(float cx, float cy, float hx, float hy,
                                          float c, float s, int idx,
                                          float& x, float& y) {
  // sgx = {+,+,-,-}[idx], sgy = {+,-,-,+}[idx]
  float sx = (idx < 2) ? 1.f : -1.f;
  float sy = (idx == 0 || idx == 3) ? 1.f : -1.f;
  float lx = sx * hx, ly = sy * hy;
  x = cx + lx * c - ly * s;
  y = cy + lx * s + ly * c;
}

__device__ __forceinline__ bool pt_in_box(float pxv, float pyv, float bx, float by,
                                          float bl, float bw, float bc, float bs) {
  float dx = pxv - bx, dy = pyv - by;
  float qx = dx * bc + dy * bs;
  float qy = -dx * bs + dy * bc;
  return (fabsf(qx) <= bl * 0.5f + 1e-5f) && (fabsf(qy) <= bw * 0.5f + 1e-5f);
}

// One wave (64 lanes) per matched pair. Lane p owns candidate point p (p<24).
__global__ __launch_bounds__(256) void pair_loss_kernel(
    const float* __restrict__ pred_boxes, const float* __restrict__ pred_ious,
    const float* __restrict__ gt_boxes, const int* __restrict__ topk_indexes,
    const int* __restrict__ batch_idx, const int* __restrict__ src_idx,
    const int* __restrict__ tgt_idx, float* __restrict__ partials) {
  const int lane = threadIdx.x & 63;
  const int wid = threadIdx.x >> 6;
  const int i = blockIdx.x * 4 + wid;  // pair id, grid = M/4 blocks

  // ---- uniform per-pair loads (broadcast within wave) ----
  const int b = batch_idx[i];
  const int s = src_idx[i];
  const int t = tgt_idx[i];
  const int tk = topk_indexes[b * K_ + s];
  const float* mp = pred_boxes + ((size_t)b * Q_ + tk) * 7;
  const float* mt = gt_boxes + ((size_t)b * G_ + t) * 7;
  const float pim = pred_ious[b * Q_ + tk];
  float A[7], Bv[7];
#pragma unroll
  for (int j = 0; j < 7; ++j) { A[j] = mp[j]; Bv[j] = mt[j]; }

  // ---- loss_bbox / loss_rad (raw boxes; computed redundantly by all lanes) ----
  float lb = 0.f;
#pragma unroll
  for (int j = 0; j < 6; ++j) lb += fabsf(A[j] - Bv[j]);
  float lr = fabsf(A[6] - Bv[6]);

  // ---- axis-aligned 3D GIoU on raw boxes (diagonal only) ----
  float lg;
  {
    float vol1 = 1.f, vol2 = 1.f, inter = 1.f, volc = 1.f;
#pragma unroll
    for (int j = 0; j < 3; ++j) {
      float l1 = A[j] - 0.5f * A[3 + j], r1 = A[j] + 0.5f * A[3 + j];
      float l2 = Bv[j] - 0.5f * Bv[3 + j], r2 = Bv[j] + 0.5f * Bv[3 + j];
      vol1 *= (r1 - l1);
      vol2 *= (r2 - l2);
      inter *= fmaxf(fminf(r1, r2) - fmaxf(l1, l2), 0.f);
      volc *= fmaxf(fmaxf(r1, r2) - fminf(l1, l2), 0.f);
    }
    float uni = vol1 + vol2 - inter;
    float iou = inter / fmaxf(uni, 1e-7f);
    lg = 1.f - (iou - (volc - uni) / fmaxf(volc, 1e-7f));
  }

  // ---- decode boxes ----
  float ax = A[0] * 150.4f - 75.2f;
  float ay = A[1] * 150.4f - 75.2f;
  float az = A[2] * 6.0f - 2.0f;
  float al = A[3] * 20.0f + 0.05f;
  float aw = A[4] * 20.0f + 0.05f;
  float ah = A[5] * 8.0f + 0.05f;
  float arad = A[6] * 6.2831853071795862f - 3.1415926535897931f;
  float bx = Bv[0] * 150.4f - 75.2f;
  float by = Bv[1] * 150.4f - 75.2f;
  float bz = Bv[2] * 6.0f - 2.0f;
  float bl = Bv[3] * 20.0f + 0.05f;
  float bw = Bv[4] * 20.0f + 0.05f;
  float bh = Bv[5] * 8.0f + 0.05f;
  float brad = Bv[6] * 6.2831853071795862f - 3.1415926535897931f;

  float cA = cosf(arad), sA = sinf(arad);
  float cB = cosf(brad), sB = sinf(brad);
  float ahx = al * 0.5f, ahy = aw * 0.5f;
  float bhx = bl * 0.5f, bhy = bw * 0.5f;

  // ---- per-lane candidate point ----
  float pxv = 0.f, pyv = 0.f;
  bool m = false;
  if (lane < 4) {
    corner_xy(ax, ay, ahx, ahy, cA, sA, lane, pxv, pyv);
    m = pt_in_box(pxv, pyv, bx, by, bl, bw, cB, sB);
  } else if (lane < 8) {
    corner_xy(bx, by, bhx, bhy, cB, sB, lane - 4, pxv, pyv);
    m = pt_in_box(pxv, pyv, ax, ay, al, aw, cA, sA);
  } else if (lane < 24) {
    int e = lane - 8;
    int j = e >> 2, k = e & 3;
    float a0x, a0y, a1x, a1y, e0x, e0y, e1x, e1y;
    corner_xy(ax, ay, ahx, ahy, cA, sA, j, a0x, a0y);
    corner_xy(ax, ay, ahx, ahy, cA, sA, (j + 1) & 3, a1x, a1y);
    corner_xy(bx, by, bhx, bhy, cB, sB, k, e0x, e0y);
    corner_xy(bx, by, bhx, bhy, cB, sB, (k + 1) & 3, e1x, e1y);
    float dax = a1x - a0x, day = a1y - a0y;
    float dbx = e1x - e0x, dby = e1y - e0y;
    float dpx = e0x - a0x, dpy = e0y - a0y;
    float den = dax * dby - day * dbx;
    bool dok = fabsf(den) > 1e-8f;
    float dens = dok ? den : 1.f;
    float tt = (dpx * dby - dpy * dbx) / dens;
    float uu = (dpx * day - dpy * dax) / dens;
    m = dok && (tt >= 0.f) && (tt <= 1.f) && (uu >= 0.f) && (uu <= 1.f);
    pxv = a0x + tt * dax;
    pyv = a0y + tt * day;
  }

  // ---- centroid over masked points (wave reduction) ----
  unsigned long long mb = __ballot(m);
  int cnt = __popcll(mb);
  float cntf = (float)cnt;
  float sx = bsum64(m ? pxv : 0.f);
  float sy = bsum64(m ? pyv : 0.f);
  float cd = fmaxf(cntf, 1.f);
  float cenx = sx / cd, ceny = sy / cd;

  // ---- angle (parallel across lanes; unmasked -> 1e9) ----
  float ap = m ? atan2f(pyv - ceny, pxv - cenx) : 1e9f;

  // ---- stable rank among the 24 candidates ----
  // Masked points have ap < 1e9, so unmasked never outrank them; stable
  // tie-break (q < lane) matches jnp.argsort's stability. Ranks of masked
  // points are exactly 0..cnt-1.
  int r = 0;
#pragma unroll
  for (int q = 0; q < 24; ++q) {
    float aq = __shfl(ap, q, 64);
    r += (aq < ap || (aq == ap && q < lane)) ? 1 : 0;
  }
  if (lane >= 24) r = lane;  // keep permutation bijective over 64 lanes

  // ---- scatter points to rank order (in-register, no scratch) ----
  float sxr = __int_as_float(__builtin_amdgcn_ds_permute(r << 2, __float_as_int(pxv)));
  float syr = __int_as_float(__builtin_amdgcn_ds_permute(r << 2, __float_as_int(pyv)));

  // ---- shoelace over sorted masked points (== reference p0-padded loop) ----
  int nidx = ((lane + 1 == cnt) ? 0 : (lane + 1)) & 63;
  float nx = __int_as_float(__builtin_amdgcn_ds_bpermute(nidx << 2, __float_as_int(sxr)));
  float ny = __int_as_float(__builtin_amdgcn_ds_bpermute(nidx << 2, __float_as_int(syr)));
  float cr = (lane < cnt) ? (sxr * ny - nx * syr) : 0.f;
  float area2 = bsum64(cr);
  float area = 0.5f * fabsf(area2);
  float inter_bev = (cnt >= 3) ? area : 0.f;

  // ---- z overlap + 3D IoU + loss_iou ----
  float zlo = fmaxf(az - ah * 0.5f, bz - bh * 0.5f);
  float zhi = fminf(az + ah * 0.5f, bz + bh * 0.5f);
  float inter3 = inter_bev * fmaxf(zhi - zlo, 0.f);
  float v1 = al * aw * ah, v2 = bl * bw * bh;
  float iou3 = inter3 / fmaxf(v1 + v2 - inter3, 1e-7f);
  float li = fabsf(pim - (iou3 * 2.f - 1.f));

  // ---- block partial: 4 waves -> 1 float4 ----
  __shared__ float wpart[4][4];
  if (lane == 0) {
    wpart[wid][0] = lb;
    wpart[wid][1] = lg;
    wpart[wid][2] = lr;
    wpart[wid][3] = li;
  }
  __syncthreads();
  if (threadIdx.x == 0) {
    float4 o;
    o.x = wpart[0][0] + wpart[1][0] + wpart[2][0] + wpart[3][0];
    o.y = wpart[0][1] + wpart[1][1] + wpart[2][1] + wpart[3][1];
    o.z = wpart[0][2] + wpart[1][2] + wpart[2][2] + wpart[3][2];
    o.w = wpart[0][3] + wpart[1][3] + wpart[2][3] + wpart[3][3];
    ((float4*)partials)[blockIdx.x] = o;
  }
}

__global__ __launch_bounds__(256) void finalize_kernel(
    const float* __restrict__ partials, const int* __restrict__ nb_ptr,
    float* __restrict__ out) {
  const int tid = threadIdx.x;
  const int lane = tid & 63;
  const int wid = tid >> 6;
  float4 acc = make_float4(0.f, 0.f, 0.f, 0.f);
#pragma unroll
  for (int k = 0; k < 4; ++k) {
    float4 p = ((const float4*)partials)[tid + 256 * k];
    acc.x += p.x; acc.y += p.y; acc.z += p.z; acc.w += p.w;
  }
  acc.x = bsum64(acc.x);
  acc.y = bsum64(acc.y);
  acc.z = bsum64(acc.z);
  acc.w = bsum64(acc.w);
  __shared__ float wpart[4][4];
  if (lane == 0) {
    wpart[wid][0] = acc.x; wpart[wid][1] = acc.y;
    wpart[wid][2] = acc.z; wpart[wid][3] = acc.w;
  }
  __syncthreads();
  if (tid == 0) {
    float nb = (float)nb_ptr[0];
    out[0] = (wpart[0][0] + wpart[1][0] + wpart[2][0] + wpart[3][0]) / nb;
    out[1] = (wpart[0][1] + wpart[1][1] + wpart[2][1] + wpart[3][1]) / nb;
    out[2] = (wpart[0][2] + wpart[1][2] + wpart[2][2] + wpart[3][2]) / nb;
    out[3] = (wpart[0][3] + wpart[1][3] + wpart[2][3] + wpart[3][3]) / nb;
  }
}

extern "C" void kernel_launch(void* const* d_in, const int* in_sizes, int n_in,
                              void* d_out, int out_size, void* d_ws, size_t ws_size,
                              hipStream_t stream) {
  const float* pred_boxes = (const float*)d_in[0];
  const float* pred_ious  = (const float*)d_in[1];
  const float* gt_boxes   = (const float*)d_in[2];
  const int* topk         = (const int*)d_in[3];
  const int* bidx         = (const int*)d_in[4];
  const int* sidx         = (const int*)d_in[5];
  const int* tidx         = (const int*)d_in[6];
  const int* nb           = (const int*)d_in[7];
  float* partials = (float*)d_ws;  // 1024 blocks * float4 = 16 KiB

  pair_loss_kernel<<<dim3(M_ / 4), dim3(256), 0, stream>>>(
      pred_boxes, pred_ious, gt_boxes, topk, bidx, sidx, tidx, partials);
  finalize_kernel<<<dim3(1), dim3(256), 0, stream>>>(partials, nb, (float*)d_out);
}

// Round 3
// 12.580 us; speedup vs baseline: 1.9319x; 1.0146x over previous
//
#include <hip/hip_runtime.h>

#define B_ 16
#define Q_ 2048
#define K_ 1024
#define G_ 512
#define M_ 4096

__device__ __forceinline__ float bsum32(float v) {
#pragma unroll
  for (int o = 1; o < 32; o <<= 1) v += __shfl_xor(v, o, 64);
  return v;  // lanes 0-31 hold sum of lanes 0-31 (and 32-63 of theirs)
}

__device__ __forceinline__ void corner_xy(float cx, float cy, float hx, float hy,
                                          float c, float s, int idx,
                                          float& x, float& y) {
  // sgx = {+,+,-,-}[idx], sgy = {+,-,-,+}[idx]
  float sx = (idx < 2) ? 1.f : -1.f;
  float sy = (idx == 0 || idx == 3) ? 1.f : -1.f;
  float lx = sx * hx, ly = sy * hy;
  x = cx + lx * c - ly * s;
  y = cy + lx * s + ly * c;
}

// One wave (64 lanes) per matched pair. Lane p owns candidate point p (p<24).
__global__ __launch_bounds__(256, 4) void pair_loss_kernel(
    const float* __restrict__ pred_boxes, const float* __restrict__ pred_ious,
    const float* __restrict__ gt_boxes, const int* __restrict__ topk_indexes,
    const int* __restrict__ batch_idx, const int* __restrict__ src_idx,
    const int* __restrict__ tgt_idx, float* __restrict__ partials) {
  const int lane = threadIdx.x & 63;
  const int wid = threadIdx.x >> 6;
  const int i = blockIdx.x * 4 + wid;  // pair id, grid = M/4 blocks

  // ---- uniform per-pair indices: force into SGPRs -> s_load for boxes ----
  const int b = __builtin_amdgcn_readfirstlane(batch_idx[i]);
  const int s = __builtin_amdgcn_readfirstlane(src_idx[i]);
  const int t = __builtin_amdgcn_readfirstlane(tgt_idx[i]);
  const int tk = __builtin_amdgcn_readfirstlane(topk_indexes[b * K_ + s]);
  const float* mp = pred_boxes + ((size_t)b * Q_ + tk) * 7;
  const float* mt = gt_boxes + ((size_t)b * G_ + t) * 7;
  const float pim = pred_ious[b * Q_ + tk];
  float A[7], Bv[7];
#pragma unroll
  for (int j = 0; j < 7; ++j) { A[j] = mp[j]; Bv[j] = mt[j]; }

  // ---- loss_bbox / loss_rad (raw boxes) ----
  float lb = 0.f;
#pragma unroll
  for (int j = 0; j < 6; ++j) lb += fabsf(A[j] - Bv[j]);
  float lr = fabsf(A[6] - Bv[6]);

  // ---- axis-aligned 3D GIoU on raw boxes (diagonal only) ----
  float lg;
  {
    float vol1 = 1.f, vol2 = 1.f, inter = 1.f, volc = 1.f;
#pragma unroll
    for (int j = 0; j < 3; ++j) {
      float l1 = A[j] - 0.5f * A[3 + j], r1 = A[j] + 0.5f * A[3 + j];
      float l2 = Bv[j] - 0.5f * Bv[3 + j], r2 = Bv[j] + 0.5f * Bv[3 + j];
      vol1 *= (r1 - l1);
      vol2 *= (r2 - l2);
      inter *= fmaxf(fminf(r1, r2) - fmaxf(l1, l2), 0.f);
      volc *= fmaxf(fmaxf(r1, r2) - fminf(l1, l2), 0.f);
    }
    float uni = vol1 + vol2 - inter;
    float iou = inter / fmaxf(uni, 1e-7f);
    lg = 1.f - (iou - (volc - uni) / fmaxf(volc, 1e-7f));
  }

  // ---- decode boxes ----
  float ax = A[0] * 150.4f - 75.2f;
  float ay = A[1] * 150.4f - 75.2f;
  float az = A[2] * 6.0f - 2.0f;
  float al = A[3] * 20.0f + 0.05f;
  float aw = A[4] * 20.0f + 0.05f;
  float ah = A[5] * 8.0f + 0.05f;
  float arad = A[6] * 6.2831853071795862f - 3.1415926535897931f;
  float bx = Bv[0] * 150.4f - 75.2f;
  float by = Bv[1] * 150.4f - 75.2f;
  float bz = Bv[2] * 6.0f - 2.0f;
  float bl = Bv[3] * 20.0f + 0.05f;
  float bw = Bv[4] * 20.0f + 0.05f;
  float bh = Bv[5] * 8.0f + 0.05f;
  float brad = Bv[6] * 6.2831853071795862f - 3.1415926535897931f;

  float cA = cosf(arad), sA = sinf(arad);
  float cB = cosf(brad), sB = sinf(brad);
  float ahx = al * 0.5f, ahy = aw * 0.5f;
  float bhx = bl * 0.5f, bhy = bw * 0.5f;

  // ---- per-lane candidate point ----
  float pxv = 0.f, pyv = 0.f;
  bool m = false;
  if (lane < 8) {
    // corners: lanes 0-3 of A (tested vs B), 4-7 of B (tested vs A)
    bool isA = lane < 4;
    int ci = lane & 3;
    float ocx = isA ? ax : bx, ocy = isA ? ay : by;
    float ohx = isA ? ahx : bhx, ohy = isA ? ahy : bhy;
    float oc = isA ? cA : cB, os = isA ? sA : sB;
    float tcx = isA ? bx : ax, tcy = isA ? by : ay;
    float tl = isA ? bl : al, tw = isA ? bw : aw;
    float tc = isA ? cB : cA, ts = isA ? sB : sA;
    corner_xy(ocx, ocy, ohx, ohy, oc, os, ci, pxv, pyv);
    float dx = pxv - tcx, dy = pyv - tcy;
    float qx = dx * tc + dy * ts;
    float qy = -dx * ts + dy * tc;
    m = (fabsf(qx) <= tl * 0.5f + 1e-5f) && (fabsf(qy) <= tw * 0.5f + 1e-5f);
  } else if (lane < 24) {
    int e = lane - 8;
    int j = e >> 2, k = e & 3;
    float a0x, a0y, a1x, a1y, e0x, e0y, e1x, e1y;
    corner_xy(ax, ay, ahx, ahy, cA, sA, j, a0x, a0y);
    corner_xy(ax, ay, ahx, ahy, cA, sA, (j + 1) & 3, a1x, a1y);
    corner_xy(bx, by, bhx, bhy, cB, sB, k, e0x, e0y);
    corner_xy(bx, by, bhx, bhy, cB, sB, (k + 1) & 3, e1x, e1y);
    float dax = a1x - a0x, day = a1y - a0y;
    float dbx = e1x - e0x, dby = e1y - e0y;
    float dpx = e0x - a0x, dpy = e0y - a0y;
    float den = dax * dby - day * dbx;
    bool dok = fabsf(den) > 1e-8f;
    float dens = dok ? den : 1.f;
    float tt = (dpx * dby - dpy * dbx) / dens;
    float uu = (dpx * day - dpy * dax) / dens;
    m = dok && (tt >= 0.f) && (tt <= 1.f) && (uu >= 0.f) && (uu <= 1.f);
    pxv = a0x + tt * dax;
    pyv = a0y + tt * day;
  }

  // ---- centroid over masked points (lanes 24-63 contribute 0) ----
  unsigned long long mb = __ballot(m);
  int cnt = __popcll(mb);
  float sx = bsum32(m ? pxv : 0.f);
  float sy = bsum32(m ? pyv : 0.f);
  float cd = fmaxf((float)cnt, 1.f);
  float cenx = sx / cd, ceny = sy / cd;  // valid on lanes 0-31 (all that matter)

  // ---- diamond pseudo-angle: strictly monotone in atan2 over [-pi,pi] ----
  // Same sort order as atan2; exact duplicates of (px,py) produce bitwise
  // equal pseudo-angles, so stable tie-break by lane matches the reference.
  float pdx = pxv - cenx, pdy = pyv - ceny;
  float ad = fabsf(pdx) + fabsf(pdy);
  float tq = pdy / ad;
  float pa = (pdx >= 0.f) ? tq : ((pdy >= 0.f) ? 2.f - tq : -2.f - tq);
  if (ad == 0.f) pa = 0.f;  // atan2(0,0)=0
  float ap = m ? pa : 1e9f;

  // ---- stable rank among the 24 candidates ----
  int r = 0;
#pragma unroll
  for (int q = 0; q < 24; ++q) {
    float aq = __shfl(ap, q, 64);
    r += (aq < ap || (aq == ap && q < lane)) ? 1 : 0;
  }
  if (lane >= 24) r = lane;  // keep permutation bijective over 64 lanes

  // ---- scatter points to rank order (in-register) ----
  float sxr = __int_as_float(__builtin_amdgcn_ds_permute(r << 2, __float_as_int(pxv)));
  float syr = __int_as_float(__builtin_amdgcn_ds_permute(r << 2, __float_as_int(pyv)));

  // ---- shoelace over sorted masked points (== reference p0-padded loop) ----
  int nidx = ((lane + 1 == cnt) ? 0 : (lane + 1)) & 63;
  float nx = __int_as_float(__builtin_amdgcn_ds_bpermute(nidx << 2, __float_as_int(sxr)));
  float ny = __int_as_float(__builtin_amdgcn_ds_bpermute(nidx << 2, __float_as_int(syr)));
  float cr = (lane < cnt) ? (sxr * ny - nx * syr) : 0.f;
  float area2 = bsum32(cr);  // lanes < 32 valid; only lane 0 consumes
  float area = 0.5f * fabsf(area2);
  float inter_bev = (cnt >= 3) ? area : 0.f;

  // ---- z overlap + 3D IoU + loss_iou ----
  float zlo = fmaxf(az - ah * 0.5f, bz - bh * 0.5f);
  float zhi = fminf(az + ah * 0.5f, bz + bh * 0.5f);
  float inter3 = inter_bev * fmaxf(zhi - zlo, 0.f);
  float v1 = al * aw * ah, v2 = bl * bw * bh;
  float iou3 = inter3 / fmaxf(v1 + v2 - inter3, 1e-7f);
  float li = fabsf(pim - (iou3 * 2.f - 1.f));

  // ---- block partial: 4 waves -> 1 float4 ----
  __shared__ float wpart[4][4];
  if (lane == 0) {
    wpart[wid][0] = lb;
    wpart[wid][1] = lg;
    wpart[wid][2] = lr;
    wpart[wid][3] = li;
  }
  __syncthreads();
  if (threadIdx.x == 0) {
    float4 o;
    o.x = wpart[0][0] + wpart[1][0] + wpart[2][0] + wpart[3][0];
    o.y = wpart[0][1] + wpart[1][1] + wpart[2][1] + wpart[3][1];
    o.z = wpart[0][2] + wpart[1][2] + wpart[2][2] + wpart[3][2];
    o.w = wpart[0][3] + wpart[1][3] + wpart[2][3] + wpart[3][3];
    ((float4*)partials)[blockIdx.x] = o;
  }
}

__global__ __launch_bounds__(256) void finalize_kernel(
    const float* __restrict__ partials, const int* __restrict__ nb_ptr,
    float* __restrict__ out) {
  const int tid = threadIdx.x;
  const int lane = tid & 63;
  const int wid = tid >> 6;
  float4 acc = make_float4(0.f, 0.f, 0.f, 0.f);
#pragma unroll
  for (int k = 0; k < 4; ++k) {
    float4 p = ((const float4*)partials)[tid + 256 * k];
    acc.x += p.x; acc.y += p.y; acc.z += p.z; acc.w += p.w;
  }
#pragma unroll
  for (int o = 1; o < 64; o <<= 1) {
    acc.x += __shfl_xor(acc.x, o, 64);
    acc.y += __shfl_xor(acc.y, o, 64);
    acc.z += __shfl_xor(acc.z, o, 64);
    acc.w += __shfl_xor(acc.w, o, 64);
  }
  __shared__ float wpart[4][4];
  if (lane == 0) {
    wpart[wid][0] = acc.x; wpart[wid][1] = acc.y;
    wpart[wid][2] = acc.z; wpart[wid][3] = acc.w;
  }
  __syncthreads();
  if (tid == 0) {
    float nb = (float)nb_ptr[0];
    out[0] = (wpart[0][0] + wpart[1][0] + wpart[2][0] + wpart[3][0]) / nb;
    out[1] = (wpart[0][1] + wpart[1][1] + wpart[2][1] + wpart[3][1]) / nb;
    out[2] = (wpart[0][2] + wpart[1][2] + wpart[2][2] + wpart[3][2]) / nb;
    out[3] = (wpart[0][3] + wpart[1][3] + wpart[2][3] + wpart[3][3]) / nb;
  }
}

extern "C" void kernel_launch(void* const* d_in, const int* in_sizes, int n_in,
                              void* d_out, int out_size, void* d_ws, size_t ws_size,
                              hipStream_t stream) {
  const float* pred_boxes = (const float*)d_in[0];
  const float* pred_ious  = (const float*)d_in[1];
  const float* gt_boxes   = (const float*)d_in[2];
  const int* topk         = (const int*)d_in[3];
  const int* bidx         = (const int*)d_in[4];
  const int* sidx         = (const int*)d_in[5];
  const int* tidx         = (const int*)d_in[6];
  const int* nb           = (const int*)d_in[7];
  float* partials = (float*)d_ws;  // 1024 blocks * float4 = 16 KiB

  pair_loss_kernel<<<dim3(M_ / 4), dim3(256), 0, stream>>>(
      pred_boxes, pred_ious, gt_boxes, topk, bidx, sidx, tidx, partials);
  finalize_kernel<<<dim3(1), dim3(256), 0, stream>>>(partials, nb, (float*)d_out);
}